// Round 9
// baseline (268.386 us; speedup 1.0000x reference)
//
#include <hip/hip_runtime.h>
#include <hip/hip_bf16.h>
#include <stdint.h>

typedef __attribute__((ext_vector_type(4))) float f32x4;
typedef __attribute__((ext_vector_type(8))) __bf16 bf16x8;

#define NROWS 1000000

__device__ __forceinline__ bf16x8 cvt8(f32x4 a, f32x4 b) {
    bf16x8 r;
    r[0] = (__bf16)a[0]; r[1] = (__bf16)a[1];
    r[2] = (__bf16)a[2]; r[3] = (__bf16)a[3];
    r[4] = (__bf16)b[0]; r[5] = (__bf16)b[1];
    r[6] = (__bf16)b[2]; r[7] = (__bf16)b[3];
    return r;
}

// out[N,64] = relu( concat(x[nidx], ht ? x[tidx] : 0) @ W^T + b )
// MFMA mapping (v_mfma_f32_16x16x32_bf16), operand-swap:
//   A = W fragment (regs): lane holds W[c][k], c = ct*16+(lane&15), k = ks*32+(lane>>4)*8+e
//   B = gathered x:        lane holds X[r][k], r = g*16+(lane&15),  same k map
//   D: col = lane&15 -> out ROW, row = (lane>>4)*4+reg -> out COL -> float4 store
// R9: R8 (depth-1 pipeline + sched_barrier fences; fences proven to kill the
//     partial-line-evict traffic cliff: FETCH 455->192MB) with occupancy
//     restored: launch_bounds (256,2)->(256,4). R8 showed pipeline alone =
//     R6's perf at HALF the waves; ILP and TLP should now multiply.
__global__ __launch_bounds__(256, 4)
void heconv_mfma(const float* __restrict__ x,
                 const int* __restrict__ nidx,
                 const int* __restrict__ tidx,
                 const int* __restrict__ ht,      // bool delivered as int32
                 const float* __restrict__ W,     // [64][128]
                 const float* __restrict__ bias,  // [64]
                 float* __restrict__ out)         // [N][64]
{
    const int lane = threadIdx.x & 63;
    const int wave = threadIdx.x >> 6;   // 0..3
    const int lrow = lane & 15;
    const int lkg  = lane >> 4;

    // W fragments in registers for the whole loop (64 VGPR)
    bf16x8 wfrag[4][4];
#pragma unroll
    for (int ct = 0; ct < 4; ++ct) {
        const float* wrow = W + (ct * 16 + lrow) * 128 + lkg * 8;
#pragma unroll
        for (int ks = 0; ks < 4; ++ks) {
            f32x4 w0 = *(const f32x4*)(wrow + ks * 32);
            f32x4 w1 = *(const f32x4*)(wrow + ks * 32 + 4);
            wfrag[ct][ks] = cvt8(w0, w1);
        }
    }
    f32x4 bfrag[4];
#pragma unroll
    for (int ct = 0; ct < 4; ++ct)
        bfrag[ct] = *(const f32x4*)(bias + ct * 16 + lkg * 4);

    const int nGroups = NROWS / 16;           // 62500
    const int gstride = gridDim.x * 4;        // 8192 waves
    const int g0 = blockIdx.x * 4 + wave;

    const f32x4 z = {0.f, 0.f, 0.f, 0.f};

    // ---- prologue: gathers(g0); idx(g0+gs) prefetched ----
    f32x4 n0, n1, n2, n3, t0, t1, t2, t3;
    if (g0 < nGroups) {
        const int r = g0 * 16 + lrow;
        const int ni = nidx[r];
        const int tv = tidx[r];
        const int hv = ht[r];
        const float* pn = x + (size_t)ni * 64 + lkg * 8;
        n0 = *(const f32x4*)(pn);
        n1 = *(const f32x4*)(pn + 4);
        n2 = *(const f32x4*)(pn + 32);
        n3 = *(const f32x4*)(pn + 36);
        t0 = z; t1 = z; t2 = z; t3 = z;
        if (hv) {
            const float* pt = x + (size_t)tv * 64 + lkg * 8;
            t0 = *(const f32x4*)(pt);
            t1 = *(const f32x4*)(pt + 4);
            t2 = *(const f32x4*)(pt + 32);
            t3 = *(const f32x4*)(pt + 36);
        }
    }
    int niN = 0, tiN = 0, hvN = 0;
    if (g0 + gstride < nGroups) {
        const int r = (g0 + gstride) * 16 + lrow;
        niN = nidx[r]; tiN = tidx[r]; hvN = ht[r];
    }

    for (int g = g0; g < nGroups; g += gstride) {
        const int gN = g + gstride;

        // ---- consume current gathers into MFMA fragments (frees n*/t*) ----
        bf16x8 xf0 = cvt8(n0, n1);
        bf16x8 xf1 = cvt8(n2, n3);
        bf16x8 xf2 = cvt8(t0, t1);
        bf16x8 xf3 = cvt8(t2, t3);

        __builtin_amdgcn_sched_barrier(0);

        // ---- issue NEXT iteration's gathers (overlap with compute below) ----
        if (gN < nGroups) {
            const float* pn = x + (size_t)niN * 64 + lkg * 8;
            n0 = *(const f32x4*)(pn);
            n1 = *(const f32x4*)(pn + 4);
            n2 = *(const f32x4*)(pn + 32);
            n3 = *(const f32x4*)(pn + 36);
            t0 = z; t1 = z; t2 = z; t3 = z;
            if (hvN) {
                const float* pt = x + (size_t)tiN * 64 + lkg * 8;
                t0 = *(const f32x4*)(pt);
                t1 = *(const f32x4*)(pt + 4);
                t2 = *(const f32x4*)(pt + 32);
                t3 = *(const f32x4*)(pt + 36);
            }
        }

        __builtin_amdgcn_sched_barrier(0);

        // ---- idx prefetch for g + 2*gstride ----
        int ni2 = 0, ti2 = 0, hv2 = 0;
        const int g2 = g + 2 * gstride;
        if (g2 < nGroups) {
            const int r = g2 * 16 + lrow;
            ni2 = nidx[r]; ti2 = tidx[r]; hv2 = ht[r];
        }

        // ---- compute + store (stores stay adjacent: only MFMAs between) ----
        const int r = g * 16 + lrow;
        bf16x8 xf[4] = { xf0, xf1, xf2, xf3 };
#pragma unroll
        for (int ct = 0; ct < 4; ++ct) {
            f32x4 acc = bfrag[ct];
#pragma unroll
            for (int ks = 0; ks < 4; ++ks)
                acc = __builtin_amdgcn_mfma_f32_16x16x32_bf16(wfrag[ct][ks], xf[ks], acc, 0, 0, 0);
            f32x4 o;
            o[0] = fmaxf(acc[0], 0.f);
            o[1] = fmaxf(acc[1], 0.f);
            o[2] = fmaxf(acc[2], 0.f);
            o[3] = fmaxf(acc[3], 0.f);
            *(f32x4*)(out + (size_t)r * 64 + ct * 16 + lkg * 4) = o;
        }

        __builtin_amdgcn_sched_barrier(0);

        niN = ni2; tiN = ti2; hvN = hv2;
    }
}

extern "C" void kernel_launch(void* const* d_in, const int* in_sizes, int n_in,
                              void* d_out, int out_size, void* d_ws, size_t ws_size,
                              hipStream_t stream) {
    const float* x    = (const float*)d_in[0];
    const int*   ni   = (const int*)d_in[1];
    const int*   ti   = (const int*)d_in[2];
    const int*   ht   = (const int*)d_in[3];
    const float* W    = (const float*)d_in[4];
    const float* bias = (const float*)d_in[5];
    float*       out  = (float*)d_out;

    heconv_mfma<<<2048, 256, 0, stream>>>(x, ni, ti, ht, W, bias, out);
}

// Round 10
// 170.404 us; speedup vs baseline: 1.5750x; 1.5750x over previous
//
#include <hip/hip_runtime.h>
#include <hip/hip_bf16.h>
#include <stdint.h>

typedef __attribute__((ext_vector_type(4))) float f32x4;
typedef __attribute__((ext_vector_type(8))) __bf16 bf16x8;

#define NROWS 1000000

__device__ __forceinline__ bf16x8 cvt8(f32x4 a, f32x4 b) {
    bf16x8 r;
    r[0] = (__bf16)a[0]; r[1] = (__bf16)a[1];
    r[2] = (__bf16)a[2]; r[3] = (__bf16)a[3];
    r[4] = (__bf16)b[0]; r[5] = (__bf16)b[1];
    r[6] = (__bf16)b[2]; r[7] = (__bf16)b[3];
    return r;
}

// out[N,64] = relu( concat(x[nidx], ht ? x[tidx] : 0) @ W^T + b )
// MFMA mapping (v_mfma_f32_16x16x32_bf16), operand-swap:
//   A = W fragment (regs): lane holds W[c][k], c = ct*16+(lane&15), k = ks*32+(lane>>4)*8+e
//   B = gathered x:        lane holds X[r][k], r = g*16+(lane&15),  same k map
//   D: col = lane&15 -> out ROW, row = (lane>>4)*4+reg -> out COL -> float4 store
// R10: R8 pipeline with launch_bounds (256,2)->(256,3).
//     Established: compiler squeezes to 64 VGPR whenever the occupancy target
//     demands it (R5/R7/R9 all report 64 VGPR + FETCH ~480-595MB) by sinking
//     the prefetch gathers into the store phase -> partial-line-evict cliff.
//     (256,3) budgets ~170 VGPR/wave — no pressure on the 96-VGPR pipeline —
//     while raising occupancy 8 -> 12 waves/CU over R8.
__global__ __launch_bounds__(256, 3)
void heconv_mfma(const float* __restrict__ x,
                 const int* __restrict__ nidx,
                 const int* __restrict__ tidx,
                 const int* __restrict__ ht,      // bool delivered as int32
                 const float* __restrict__ W,     // [64][128]
                 const float* __restrict__ bias,  // [64]
                 float* __restrict__ out)         // [N][64]
{
    const int lane = threadIdx.x & 63;
    const int wave = threadIdx.x >> 6;   // 0..3
    const int lrow = lane & 15;
    const int lkg  = lane >> 4;

    // W fragments in registers for the whole loop (64 VGPR)
    bf16x8 wfrag[4][4];
#pragma unroll
    for (int ct = 0; ct < 4; ++ct) {
        const float* wrow = W + (ct * 16 + lrow) * 128 + lkg * 8;
#pragma unroll
        for (int ks = 0; ks < 4; ++ks) {
            f32x4 w0 = *(const f32x4*)(wrow + ks * 32);
            f32x4 w1 = *(const f32x4*)(wrow + ks * 32 + 4);
            wfrag[ct][ks] = cvt8(w0, w1);
        }
    }
    f32x4 bfrag[4];
#pragma unroll
    for (int ct = 0; ct < 4; ++ct)
        bfrag[ct] = *(const f32x4*)(bias + ct * 16 + lkg * 4);

    const int nGroups = NROWS / 16;           // 62500
    const int gstride = gridDim.x * 4;        // 8192 waves
    const int g0 = blockIdx.x * 4 + wave;

    const f32x4 z = {0.f, 0.f, 0.f, 0.f};

    // ---- prologue: gathers(g0); idx(g0+gs) prefetched ----
    f32x4 n0, n1, n2, n3, t0, t1, t2, t3;
    if (g0 < nGroups) {
        const int r = g0 * 16 + lrow;
        const int ni = nidx[r];
        const int tv = tidx[r];
        const int hv = ht[r];
        const float* pn = x + (size_t)ni * 64 + lkg * 8;
        n0 = *(const f32x4*)(pn);
        n1 = *(const f32x4*)(pn + 4);
        n2 = *(const f32x4*)(pn + 32);
        n3 = *(const f32x4*)(pn + 36);
        t0 = z; t1 = z; t2 = z; t3 = z;
        if (hv) {
            const float* pt = x + (size_t)tv * 64 + lkg * 8;
            t0 = *(const f32x4*)(pt);
            t1 = *(const f32x4*)(pt + 4);
            t2 = *(const f32x4*)(pt + 32);
            t3 = *(const f32x4*)(pt + 36);
        }
    }
    int niN = 0, tiN = 0, hvN = 0;
    if (g0 + gstride < nGroups) {
        const int r = (g0 + gstride) * 16 + lrow;
        niN = nidx[r]; tiN = tidx[r]; hvN = ht[r];
    }

    for (int g = g0; g < nGroups; g += gstride) {
        const int gN = g + gstride;

        // ---- consume current gathers into MFMA fragments (frees n*/t*) ----
        bf16x8 xf0 = cvt8(n0, n1);
        bf16x8 xf1 = cvt8(n2, n3);
        bf16x8 xf2 = cvt8(t0, t1);
        bf16x8 xf3 = cvt8(t2, t3);

        __builtin_amdgcn_sched_barrier(0);

        // ---- issue NEXT iteration's gathers (overlap with compute below) ----
        if (gN < nGroups) {
            const float* pn = x + (size_t)niN * 64 + lkg * 8;
            n0 = *(const f32x4*)(pn);
            n1 = *(const f32x4*)(pn + 4);
            n2 = *(const f32x4*)(pn + 32);
            n3 = *(const f32x4*)(pn + 36);
            t0 = z; t1 = z; t2 = z; t3 = z;
            if (hvN) {
                const float* pt = x + (size_t)tiN * 64 + lkg * 8;
                t0 = *(const f32x4*)(pt);
                t1 = *(const f32x4*)(pt + 4);
                t2 = *(const f32x4*)(pt + 32);
                t3 = *(const f32x4*)(pt + 36);
            }
        }

        __builtin_amdgcn_sched_barrier(0);

        // ---- idx prefetch for g + 2*gstride ----
        int ni2 = 0, ti2 = 0, hv2 = 0;
        const int g2 = g + 2 * gstride;
        if (g2 < nGroups) {
            const int r = g2 * 16 + lrow;
            ni2 = nidx[r]; ti2 = tidx[r]; hv2 = ht[r];
        }

        // ---- compute + store (stores stay adjacent: only MFMAs between) ----
        const int r = g * 16 + lrow;
        bf16x8 xf[4] = { xf0, xf1, xf2, xf3 };
#pragma unroll
        for (int ct = 0; ct < 4; ++ct) {
            f32x4 acc = bfrag[ct];
#pragma unroll
            for (int ks = 0; ks < 4; ++ks)
                acc = __builtin_amdgcn_mfma_f32_16x16x32_bf16(wfrag[ct][ks], xf[ks], acc, 0, 0, 0);
            f32x4 o;
            o[0] = fmaxf(acc[0], 0.f);
            o[1] = fmaxf(acc[1], 0.f);
            o[2] = fmaxf(acc[2], 0.f);
            o[3] = fmaxf(acc[3], 0.f);
            *(f32x4*)(out + (size_t)r * 64 + ct * 16 + lkg * 4) = o;
        }

        __builtin_amdgcn_sched_barrier(0);

        niN = ni2; tiN = ti2; hvN = hv2;
    }
}

extern "C" void kernel_launch(void* const* d_in, const int* in_sizes, int n_in,
                              void* d_out, int out_size, void* d_ws, size_t ws_size,
                              hipStream_t stream) {
    const float* x    = (const float*)d_in[0];
    const int*   ni   = (const int*)d_in[1];
    const int*   ti   = (const int*)d_in[2];
    const int*   ht   = (const int*)d_in[3];
    const float* W    = (const float*)d_in[4];
    const float* bias = (const float*)d_in[5];
    float*       out  = (float*)d_out;

    heconv_mfma<<<2048, 256, 0, stream>>>(x, ni, ti, ht, W, bias, out);
}

// Round 11
// 137.127 us; speedup vs baseline: 1.9572x; 1.2427x over previous
//
#include <hip/hip_runtime.h>
#include <hip/hip_bf16.h>
#include <stdint.h>

typedef __attribute__((ext_vector_type(4))) float f32x4;
typedef __attribute__((ext_vector_type(8))) __bf16 bf16x8;

#define NROWS 1000000

__device__ __forceinline__ bf16x8 cvt8(f32x4 a, f32x4 b) {
    bf16x8 r;
    r[0] = (__bf16)a[0]; r[1] = (__bf16)a[1];
    r[2] = (__bf16)a[2]; r[3] = (__bf16)a[3];
    r[4] = (__bf16)b[0]; r[5] = (__bf16)b[1];
    r[6] = (__bf16)b[2]; r[7] = (__bf16)b[3];
    return r;
}

// out[N,64] = relu( concat(x[nidx], ht ? x[tidx] : 0) @ W^T + b )
// MFMA mapping (v_mfma_f32_16x16x32_bf16), operand-swap:
//   A = W fragment (regs): lane holds W[c][k], c = ct*16+(lane&15), k = ks*32+(lane>>4)*8+e
//   B = gathered x:        lane holds X[r][k], r = g*16+(lane&15),  same k map
//   D: col = lane&15 -> out ROW, row = (lane>>4)*4+reg -> out COL -> float4 store
// R11: depth-2 software pipeline at (256,2). Two payload register sets (A/B);
//     gathers issue TWO groups ahead of consumption so ~2 compute+store phases
//     (~500cy) cover gather latency. Same per-phase fence structure as R8
//     (proven cliff-free: FETCH 192MB). Grid 512 = exact residency at
//     2 blocks/CU -> 30 groups/wave, prologue + W-load amortized.
//     Learned R8/R9/R10: launch_bounds >2 blocks/CU makes the compiler shave
//     VGPRs by sinking gathers into the store phase -> partial-line-evict
//     cliff (FETCH 480-595MB). Stay at (256,2); scale ILP, not waves.
__global__ __launch_bounds__(256, 2)
void heconv_mfma(const float* __restrict__ x,
                 const int* __restrict__ nidx,
                 const int* __restrict__ tidx,
                 const int* __restrict__ ht,      // bool delivered as int32
                 const float* __restrict__ W,     // [64][128]
                 const float* __restrict__ bias,  // [64]
                 float* __restrict__ out)         // [N][64]
{
    const int lane = threadIdx.x & 63;
    const int wave = threadIdx.x >> 6;   // 0..3
    const int lrow = lane & 15;
    const int lkg  = lane >> 4;

    // W fragments in registers for the whole loop (64 VGPR)
    bf16x8 wfrag[4][4];
#pragma unroll
    for (int ct = 0; ct < 4; ++ct) {
        const float* wrow = W + (ct * 16 + lrow) * 128 + lkg * 8;
#pragma unroll
        for (int ks = 0; ks < 4; ++ks) {
            f32x4 w0 = *(const f32x4*)(wrow + ks * 32);
            f32x4 w1 = *(const f32x4*)(wrow + ks * 32 + 4);
            wfrag[ct][ks] = cvt8(w0, w1);
        }
    }
    f32x4 bfrag[4];
#pragma unroll
    for (int ct = 0; ct < 4; ++ct)
        bfrag[ct] = *(const f32x4*)(bias + ct * 16 + lkg * 4);

    const int nGroups = NROWS / 16;           // 62500
    const int S  = gridDim.x * 4;             // 2048 waves
    const int g0 = blockIdx.x * 4 + wave;

    const f32x4 z = {0.f, 0.f, 0.f, 0.f};

    // ---- payload register sets ----
    f32x4 pAn0, pAn1, pAn2, pAn3, pAt0, pAt1, pAt2, pAt3;
    f32x4 pBn0, pBn1, pBn2, pBn3, pBt0, pBt1, pBt2, pBt3;

    // ---- prologue: gather g0 -> payA, g0+S -> payB ----
    {
        const int r = g0 * 16 + lrow;
        const int ni = nidx[r], tv = tidx[r], hv = ht[r];
        const float* pn = x + (size_t)ni * 64 + lkg * 8;
        pAn0 = *(const f32x4*)(pn);
        pAn1 = *(const f32x4*)(pn + 4);
        pAn2 = *(const f32x4*)(pn + 32);
        pAn3 = *(const f32x4*)(pn + 36);
        pAt0 = z; pAt1 = z; pAt2 = z; pAt3 = z;
        if (hv) {
            const float* pt = x + (size_t)tv * 64 + lkg * 8;
            pAt0 = *(const f32x4*)(pt);
            pAt1 = *(const f32x4*)(pt + 4);
            pAt2 = *(const f32x4*)(pt + 32);
            pAt3 = *(const f32x4*)(pt + 36);
        }
    }
    pBn0 = z; pBn1 = z; pBn2 = z; pBn3 = z;
    pBt0 = z; pBt1 = z; pBt2 = z; pBt3 = z;
    if (g0 + S < nGroups) {
        const int r = (g0 + S) * 16 + lrow;
        const int ni = nidx[r], tv = tidx[r], hv = ht[r];
        const float* pn = x + (size_t)ni * 64 + lkg * 8;
        pBn0 = *(const f32x4*)(pn);
        pBn1 = *(const f32x4*)(pn + 4);
        pBn2 = *(const f32x4*)(pn + 32);
        pBn3 = *(const f32x4*)(pn + 36);
        if (hv) {
            const float* pt = x + (size_t)tv * 64 + lkg * 8;
            pBt0 = *(const f32x4*)(pt);
            pBt1 = *(const f32x4*)(pt + 4);
            pBt2 = *(const f32x4*)(pt + 32);
            pBt3 = *(const f32x4*)(pt + 36);
        }
    }

    // ---- prefetched indices: idxA for g0+2S, idxB for g0+3S ----
    int aNi = 0, aTi = 0, aHv = 0, bNi = 0, bTi = 0, bHv = 0;
    if (g0 + 2 * S < nGroups) {
        const int r = (g0 + 2 * S) * 16 + lrow;
        aNi = nidx[r]; aTi = tidx[r]; aHv = ht[r];
    }
    if (g0 + 3 * S < nGroups) {
        const int r = (g0 + 3 * S) * 16 + lrow;
        bNi = nidx[r]; bTi = tidx[r]; bHv = ht[r];
    }

    for (int g = g0; g < nGroups; g += 2 * S) {
        // ================= phase A: group g =================
        {
            bf16x8 xf0 = cvt8(pAn0, pAn1);
            bf16x8 xf1 = cvt8(pAn2, pAn3);
            bf16x8 xf2 = cvt8(pAt0, pAt1);
            bf16x8 xf3 = cvt8(pAt2, pAt3);

            __builtin_amdgcn_sched_barrier(0);

            if (g + 2 * S < nGroups) {   // re-gather payA for group g+2S
                const float* pn = x + (size_t)aNi * 64 + lkg * 8;
                pAn0 = *(const f32x4*)(pn);
                pAn1 = *(const f32x4*)(pn + 4);
                pAn2 = *(const f32x4*)(pn + 32);
                pAn3 = *(const f32x4*)(pn + 36);
                pAt0 = z; pAt1 = z; pAt2 = z; pAt3 = z;
                if (aHv) {
                    const float* pt = x + (size_t)aTi * 64 + lkg * 8;
                    pAt0 = *(const f32x4*)(pt);
                    pAt1 = *(const f32x4*)(pt + 4);
                    pAt2 = *(const f32x4*)(pt + 32);
                    pAt3 = *(const f32x4*)(pt + 36);
                }
            }

            __builtin_amdgcn_sched_barrier(0);

            // idx prefetch for g+4S (consumed in 1 loop iteration)
            aNi = 0; aTi = 0; aHv = 0;
            if (g + 4 * S < nGroups) {
                const int r = (g + 4 * S) * 16 + lrow;
                aNi = nidx[r]; aTi = tidx[r]; aHv = ht[r];
            }

            const int r = g * 16 + lrow;
            bf16x8 xf[4] = { xf0, xf1, xf2, xf3 };
#pragma unroll
            for (int ct = 0; ct < 4; ++ct) {
                f32x4 acc = bfrag[ct];
#pragma unroll
                for (int ks = 0; ks < 4; ++ks)
                    acc = __builtin_amdgcn_mfma_f32_16x16x32_bf16(wfrag[ct][ks], xf[ks], acc, 0, 0, 0);
                f32x4 o;
                o[0] = fmaxf(acc[0], 0.f);
                o[1] = fmaxf(acc[1], 0.f);
                o[2] = fmaxf(acc[2], 0.f);
                o[3] = fmaxf(acc[3], 0.f);
                *(f32x4*)(out + (size_t)r * 64 + ct * 16 + lkg * 4) = o;
            }

            __builtin_amdgcn_sched_barrier(0);
        }

        // ================= phase B: group g+S =================
        if (g + S < nGroups) {
            bf16x8 xf0 = cvt8(pBn0, pBn1);
            bf16x8 xf1 = cvt8(pBn2, pBn3);
            bf16x8 xf2 = cvt8(pBt0, pBt1);
            bf16x8 xf3 = cvt8(pBt2, pBt3);

            __builtin_amdgcn_sched_barrier(0);

            if (g + 3 * S < nGroups) {   // re-gather payB for group g+3S
                const float* pn = x + (size_t)bNi * 64 + lkg * 8;
                pBn0 = *(const f32x4*)(pn);
                pBn1 = *(const f32x4*)(pn + 4);
                pBn2 = *(const f32x4*)(pn + 32);
                pBn3 = *(const f32x4*)(pn + 36);
                pBt0 = z; pBt1 = z; pBt2 = z; pBt3 = z;
                if (bHv) {
                    const float* pt = x + (size_t)bTi * 64 + lkg * 8;
                    pBt0 = *(const f32x4*)(pt);
                    pBt1 = *(const f32x4*)(pt + 4);
                    pBt2 = *(const f32x4*)(pt + 32);
                    pBt3 = *(const f32x4*)(pt + 36);
                }
            }

            __builtin_amdgcn_sched_barrier(0);

            // idx prefetch for g+5S
            bNi = 0; bTi = 0; bHv = 0;
            if (g + 5 * S < nGroups) {
                const int r = (g + 5 * S) * 16 + lrow;
                bNi = nidx[r]; bTi = tidx[r]; bHv = ht[r];
            }

            const int r = (g + S) * 16 + lrow;
            bf16x8 xf[4] = { xf0, xf1, xf2, xf3 };
#pragma unroll
            for (int ct = 0; ct < 4; ++ct) {
                f32x4 acc = bfrag[ct];
#pragma unroll
                for (int ks = 0; ks < 4; ++ks)
                    acc = __builtin_amdgcn_mfma_f32_16x16x32_bf16(wfrag[ct][ks], xf[ks], acc, 0, 0, 0);
                f32x4 o;
                o[0] = fmaxf(acc[0], 0.f);
                o[1] = fmaxf(acc[1], 0.f);
                o[2] = fmaxf(acc[2], 0.f);
                o[3] = fmaxf(acc[3], 0.f);
                *(f32x4*)(out + (size_t)r * 64 + ct * 16 + lkg * 4) = o;
            }

            __builtin_amdgcn_sched_barrier(0);
        }
    }
}

extern "C" void kernel_launch(void* const* d_in, const int* in_sizes, int n_in,
                              void* d_out, int out_size, void* d_ws, size_t ws_size,
                              hipStream_t stream) {
    const float* x    = (const float*)d_in[0];
    const int*   ni   = (const int*)d_in[1];
    const int*   ti   = (const int*)d_in[2];
    const int*   ht   = (const int*)d_in[3];
    const float* W    = (const float*)d_in[4];
    const float* bias = (const float*)d_in[5];
    float*       out  = (float*)d_out;

    heconv_mfma<<<512, 256, 0, stream>>>(x, ni, ti, ht, W, bias, out);
}